// Round 8
// baseline (793.237 us; speedup 1.0000x reference)
//
#include <hip/hip_runtime.h>
#include <math.h>

#define B_   4
#define S_   2048
#define AD   128
#define NH   4
#define HD   32
#define TK   32
#define SEG  1048576            /* 8192*128 */
#define CAP  192                /* survivor capacity per row */

#define OFF_PROJ 0
#define OFF_Q    (1 * SEG)
#define OFF_K    (2 * SEG)
#define OFF_V    (3 * SEG)
#define OFF_ATT  (4 * SEG)
#define OFF_T    (5 * SEG)
#define OFF_SB   (6 * SEG)
#define OFF_CAT  (7 * SEG)      /* 2*SEG floats */

__device__ float g_ws[9 * SEG];

__device__ __forceinline__ unsigned f2key(float s) {
    unsigned u = __float_as_uint(s);
    return (u & 0x80000000u) ? ~u : (u | 0x80000000u);
}
__device__ __forceinline__ float key2f(unsigned k) {
    unsigned u = (k & 0x80000000u) ? (k & 0x7FFFFFFFu) : ~k;
    return __uint_as_float(u);
}
__device__ __forceinline__ float rfl(float x) {
    return __uint_as_float(__builtin_amdgcn_readfirstlane(__float_as_uint(x)));
}

// Y[M x 128] = X[M x KD] @ W[128 x KD]^T + b (R5 known-good version, pad 68)
template <int KD>
__global__ __launch_bounds__(256)
void lin_kernel(const float* __restrict__ Xext, int xoff,
                const float* __restrict__ W, const float* __restrict__ Bv,
                int yoff)
{
    const float* X = Xext ? Xext : (const float*)(g_ws + xoff);
    float* Y = g_ws + yoff;
    __shared__ float Xs[32][68];
    __shared__ float Ws[32][68];
    const int bm = blockIdx.x * 64;
    const int bn = blockIdx.y * 64;
    const int t  = threadIdx.x;
    const int tx = t & 15, ty = t >> 4;
    const int sr = t >> 3, sc4 = t & 7;
    float acc[4][4] = {};
    for (int kk = 0; kk < KD; kk += 32) {
        #pragma unroll
        for (int it = 0; it < 2; ++it) {
            int rr = sr + it * 32;
            float4 xa = *(const float4*)(X + (size_t)(bm + rr) * KD + kk + sc4 * 4);
            float4 wa = *(const float4*)(W + (size_t)(bn + rr) * KD + kk + sc4 * 4);
            Xs[sc4*4+0][rr] = xa.x; Xs[sc4*4+1][rr] = xa.y;
            Xs[sc4*4+2][rr] = xa.z; Xs[sc4*4+3][rr] = xa.w;
            Ws[sc4*4+0][rr] = wa.x; Ws[sc4*4+1][rr] = wa.y;
            Ws[sc4*4+2][rr] = wa.z; Ws[sc4*4+3][rr] = wa.w;
        }
        __syncthreads();
        #pragma unroll
        for (int kc = 0; kc < 32; ++kc) {
            float4 a4 = *(const float4*)&Xs[kc][ty * 4];
            float4 b4 = *(const float4*)&Ws[kc][tx * 4];
            float a[4] = {a4.x, a4.y, a4.z, a4.w};
            float bb[4] = {b4.x, b4.y, b4.z, b4.w};
            #pragma unroll
            for (int i = 0; i < 4; ++i)
                #pragma unroll
                for (int j = 0; j < 4; ++j)
                    acc[i][j] = fmaf(a[i], bb[j], acc[i][j]);
        }
        __syncthreads();
    }
    #pragma unroll
    for (int i = 0; i < 4; ++i) {
        int row = bm + ty * 4 + i;
        int col = bn + tx * 4;
        float4 o;
        o.x = acc[i][0] + Bv[col + 0]; o.y = acc[i][1] + Bv[col + 1];
        o.z = acc[i][2] + Bv[col + 2]; o.w = acc[i][3] + Bv[col + 3];
        *(float4*)(Y + (size_t)row * AD + col) = o;
    }
}

template <int KD>
__global__ __launch_bounds__(256)
void lin3_kernel(int xoff,
                 const float* __restrict__ W0, const float* __restrict__ B0, int y0,
                 const float* __restrict__ W1, const float* __restrict__ B1, int y1,
                 const float* __restrict__ W2, const float* __restrict__ B2, int y2)
{
    const int z = blockIdx.z;
    const float* X = (const float*)(g_ws + xoff);
    const float* W = (z == 0) ? W0 : (z == 1) ? W1 : W2;
    const float* Bv = (z == 0) ? B0 : (z == 1) ? B1 : B2;
    float* Y = g_ws + ((z == 0) ? y0 : (z == 1) ? y1 : y2);
    __shared__ float Xs[32][68];
    __shared__ float Ws[32][68];
    const int bm = blockIdx.x * 64;
    const int bn = blockIdx.y * 64;
    const int t  = threadIdx.x;
    const int tx = t & 15, ty = t >> 4;
    const int sr = t >> 3, sc4 = t & 7;
    float acc[4][4] = {};
    for (int kk = 0; kk < KD; kk += 32) {
        #pragma unroll
        for (int it = 0; it < 2; ++it) {
            int rr = sr + it * 32;
            float4 xa = *(const float4*)(X + (size_t)(bm + rr) * KD + kk + sc4 * 4);
            float4 wa = *(const float4*)(W + (size_t)(bn + rr) * KD + kk + sc4 * 4);
            Xs[sc4*4+0][rr] = xa.x; Xs[sc4*4+1][rr] = xa.y;
            Xs[sc4*4+2][rr] = xa.z; Xs[sc4*4+3][rr] = xa.w;
            Ws[sc4*4+0][rr] = wa.x; Ws[sc4*4+1][rr] = wa.y;
            Ws[sc4*4+2][rr] = wa.z; Ws[sc4*4+3][rr] = wa.w;
        }
        __syncthreads();
        #pragma unroll
        for (int kc = 0; kc < 32; ++kc) {
            float4 a4 = *(const float4*)&Xs[kc][ty * 4];
            float4 b4 = *(const float4*)&Ws[kc][tx * 4];
            float a[4] = {a4.x, a4.y, a4.z, a4.w};
            float bb[4] = {b4.x, b4.y, b4.z, b4.w};
            #pragma unroll
            for (int i = 0; i < 4; ++i)
                #pragma unroll
                for (int j = 0; j < 4; ++j)
                    acc[i][j] = fmaf(a[i], bb[j], acc[i][j]);
        }
        __syncthreads();
    }
    #pragma unroll
    for (int i = 0; i < 4; ++i) {
        int row = bm + ty * 4 + i;
        int col = bn + tx * 4;
        float4 o;
        o.x = acc[i][0] + Bv[col + 0]; o.y = acc[i][1] + Bv[col + 1];
        o.z = acc[i][2] + Bv[col + 2]; o.w = acc[i][3] + Bv[col + 3];
        *(float4*)(Y + (size_t)row * AD + col) = o;
    }
}

// Exact top-32 of one score row (keys in regs, j = t*64+lane):
// threshold-prefilter + rank-by-count; set == lax.top_k set.
__device__ __forceinline__ void select_row(const unsigned (&keys)[32],
                                           unsigned long long* sv,
                                           float* wp, unsigned* jp,
                                           int lane, unsigned thr, float Mf)
{
    asm volatile("s_waitcnt lgkmcnt(0)" ::: "memory");
    int base = 0;
    const unsigned long long lt = (1ull << lane) - 1ull;
    #pragma unroll
    for (int t = 0; t < 32; ++t) {
        bool pred = keys[t] >= thr;
        unsigned long long m = __ballot(pred);
        int slot = base + __popcll(m & lt);
        if (pred && slot < CAP) {
            unsigned jidx = (unsigned)(t * 64 + lane);
            sv[slot] = ((unsigned long long)keys[t] << 32) | (unsigned)(2047 - jidx);
        }
        base += __popcll(m);
    }
    const int S = base;
    asm volatile("s_waitcnt lgkmcnt(0)" ::: "memory");

    if (S <= 64) {
        unsigned long long pi = (lane < S) ? sv[lane] : 0ull;
        int rank = 0;
        for (int jx = 0; jx < S; ++jx)
            rank += (sv[jx] > pi) ? 1 : 0;
        float e = 0.f; unsigned ji = 0;
        if (lane < S && rank < TK) {
            float val = key2f((unsigned)(pi >> 32));
            e = __expf(val - Mf);
            ji = 2047u - (unsigned)(pi & 0xFFFFFFFFull);
        }
        float esum = e;
        #pragma unroll
        for (int off = 1; off < 64; off <<= 1) esum += __shfl_xor(esum, off);
        if (lane < S && rank < TK) { wp[rank] = e / esum; jp[rank] = ji; }
    } else if (S <= CAP) {
        unsigned long long pi[3]; int rk[3]; float ee[3]; unsigned jj[3];
        float esum = 0.f;
        #pragma unroll
        for (int u = 0; u < 3; ++u) {
            int i = lane + u * 64;
            pi[u] = (i < S) ? sv[i] : 0ull;
            rk[u] = 0; ee[u] = 0.f; jj[u] = 0;
        }
        for (int jx = 0; jx < S; ++jx) {
            unsigned long long pj = sv[jx];
            #pragma unroll
            for (int u = 0; u < 3; ++u)
                rk[u] += (pj > pi[u]) ? 1 : 0;
        }
        #pragma unroll
        for (int u = 0; u < 3; ++u) {
            int i = lane + u * 64;
            if (i < S && rk[u] < TK) {
                float val = key2f((unsigned)(pi[u] >> 32));
                ee[u] = __expf(val - Mf);
                jj[u] = 2047u - (unsigned)(pi[u] & 0xFFFFFFFFull);
                esum += ee[u];
            }
        }
        #pragma unroll
        for (int off = 1; off < 64; off <<= 1) esum += __shfl_xor(esum, off);
        #pragma unroll
        for (int u = 0; u < 3; ++u) {
            int i = lane + u * 64;
            if (i < S && rk[u] < TK) { wp[rk[u]] = ee[u] / esum; jp[rk[u]] = jj[u]; }
        }
    } else {
        // exact fallback: iterative argmax (value desc, idx asc)
        unsigned consumed = 0u;
        for (int i = 0; i < TK; ++i) {
            unsigned bk = 0u; unsigned gj = 0xFFFFFFFFu;
            #pragma unroll
            for (int t = 0; t < 32; ++t) {
                if (((consumed >> t) & 1u) == 0u) {
                    unsigned kk = keys[t];
                    unsigned j = (unsigned)(t * 64 + lane);
                    if (kk > bk || (kk == bk && j < gj)) { bk = kk; gj = j; }
                }
            }
            #pragma unroll
            for (int off = 1; off < 64; off <<= 1) {
                unsigned ok = (unsigned)__shfl_xor((int)bk, off);
                unsigned oj = (unsigned)__shfl_xor((int)gj, off);
                if (ok > bk || (ok == bk && oj < gj)) { bk = ok; gj = oj; }
            }
            if ((gj & 63u) == (unsigned)lane && gj != 0xFFFFFFFFu)
                consumed |= (1u << (gj >> 6));
            if (lane == 0) { wp[i] = key2f(bk); jp[i] = gj; }
        }
        asm volatile("s_waitcnt lgkmcnt(0)" ::: "memory");
        float v = (lane < TK) ? wp[lane] : 0.f;
        float e = (lane < TK) ? __expf(v - Mf) : 0.f;
        float esum = e;
        #pragma unroll
        for (int off = 1; off < 64; off <<= 1) esum += __shfl_xor(esum, off);
        if (lane < TK) wp[lane] = e / esum;
    }
    asm volatile("s_waitcnt lgkmcnt(0)" ::: "memory");
}

// Fused score + exact top-32 + softmax + V-gather. Block = 4 waves, 8 q-rows
// (2/wave), one head. K streamed via double-buffered swizzled LDS tiles.
__global__ __launch_bounds__(256)
void fused_attn(int qoff, int koff, int voff, int ooff)
{
    __shared__ float4 Ks[2][64][8];
    __shared__ unsigned long long sve[4][CAP];
    __shared__ float    wsel[4][32];
    __shared__ unsigned jsel[4][32];

    const int tid  = threadIdx.x;
    const int wid  = tid >> 6;
    const int lane = tid & 63;
    const int hh   = blockIdx.y;          // 0..15
    const int b    = hh >> 2, h = hh & 3;
    const int r0   = blockIdx.x * 8 + wid * 2;

    const float* Qb    = g_ws + qoff + (size_t)b * S_ * AD + h * HD;
    const float* Kb    = g_ws + koff + (size_t)b * S_ * AD + h * HD;
    const float* vbase = g_ws + voff + (size_t)b * S_ * AD + h * HD;
    float* O = g_ws + ooff;

    const float scale = 0.17677669529663688f;  // 1/sqrt(32), monotone

    // q rows (wave-uniform) -> scalar regs, pre-scaled
    float qs0[32], qs1[32];
    #pragma unroll
    for (int g = 0; g < 8; ++g) {
        float4 qa = *(const float4*)(Qb + (size_t)r0 * AD + g * 4);
        float4 qb = *(const float4*)(Qb + (size_t)(r0 + 1) * AD + g * 4);
        qs0[g*4+0] = rfl(qa.x) * scale; qs0[g*4+1] = rfl(qa.y) * scale;
        qs0[g*4+2] = rfl(qa.z) * scale; qs0[g*4+3] = rfl(qa.w) * scale;
        qs1[g*4+0] = rfl(qb.x) * scale; qs1[g*4+1] = rfl(qb.y) * scale;
        qs1[g*4+2] = rfl(qb.z) * scale; qs1[g*4+3] = rfl(qb.w) * scale;
    }

    // staging geometry: thread stages 8 consecutive floats of K-tile row tid>>2
    const int srow = tid >> 2;
    const int sgp  = (tid & 3) * 2;
    const int sg0  = sgp ^ (srow & 7);
    const int sg1  = (sgp + 1) ^ (srow & 7);
    const size_t sbase = (size_t)srow * AD + sgp * 4;

    // prologue: stage tile 0 into buf 0
    {
        float4 a = *(const float4*)(Kb + sbase);
        float4 c = *(const float4*)(Kb + sbase + 4);
        Ks[0][srow][sg0] = a;
        Ks[0][srow][sg1] = c;
    }
    __syncthreads();

    unsigned keys0[32], keys1[32];
    unsigned lmax0 = 0u, lmax1 = 0u;
    const int l7 = lane & 7;

    #pragma unroll
    for (int t = 0; t < 32; ++t) {
        const int cur = t & 1;
        if (t < 31) {  // stage next tile into other buffer
            float4 a = *(const float4*)(Kb + (size_t)(t + 1) * 64 * AD + sbase);
            float4 c = *(const float4*)(Kb + (size_t)(t + 1) * 64 * AD + sbase + 4);
            Ks[cur ^ 1][srow][sg0] = a;
            Ks[cur ^ 1][srow][sg1] = c;
        }
        float s0 = 0.f, s1 = 0.f;
        #pragma unroll
        for (int g = 0; g < 8; ++g) {
            float4 kv = Ks[cur][lane][g ^ l7];
            s0 = fmaf(qs0[g*4+0], kv.x, s0); s0 = fmaf(qs0[g*4+1], kv.y, s0);
            s0 = fmaf(qs0[g*4+2], kv.z, s0); s0 = fmaf(qs0[g*4+3], kv.w, s0);
            s1 = fmaf(qs1[g*4+0], kv.x, s1); s1 = fmaf(qs1[g*4+1], kv.y, s1);
            s1 = fmaf(qs1[g*4+2], kv.z, s1); s1 = fmaf(qs1[g*4+3], kv.w, s1);
        }
        unsigned k0 = f2key(s0), k1 = f2key(s1);
        keys0[t] = k0; keys1[t] = k1;
        lmax0 = (k0 > lmax0) ? k0 : lmax0;
        lmax1 = (k1 > lmax1) ? k1 : lmax1;
        __syncthreads();
    }

    // interleaved bitonic sort (ascending) of lane maxima, both rows
    unsigned bs0 = lmax0, bs1 = lmax1;
    #pragma unroll
    for (int k = 2; k <= 64; k <<= 1) {
        #pragma unroll
        for (int j = k >> 1; j > 0; j >>= 1) {
            unsigned o0 = (unsigned)__shfl_xor((int)bs0, j);
            unsigned o1 = (unsigned)__shfl_xor((int)bs1, j);
            bool keepmin = (((lane & k) == 0) == ((lane & j) == 0));
            bs0 = keepmin ? (bs0 < o0 ? bs0 : o0) : (bs0 > o0 ? bs0 : o0);
            bs1 = keepmin ? (bs1 < o1 ? bs1 : o1) : (bs1 > o1 ? bs1 : o1);
        }
    }
    const unsigned thr0 = (unsigned)__shfl((int)bs0, 32);
    const unsigned thr1 = (unsigned)__shfl((int)bs1, 32);
    const float Mf0 = key2f((unsigned)__shfl((int)bs0, 63));
    const float Mf1 = key2f((unsigned)__shfl((int)bs1, 63));

    const int dd = lane & 31, half = lane >> 5;

    // row 0
    select_row(keys0, sve[wid], wsel[wid], jsel[wid], lane, thr0, Mf0);
    {
        float oacc = 0.f;
        #pragma unroll
        for (int u = 0; u < 16; ++u) {
            int i = half * 16 + u;
            oacc = fmaf(wsel[wid][i], vbase[(size_t)jsel[wid][i] * AD + dd], oacc);
        }
        oacc += __shfl_down(oacc, 32);
        if (lane < HD) O[((size_t)b * S_ + r0) * AD + h * HD + lane] = oacc;
    }
    // row 1
    select_row(keys1, sve[wid], wsel[wid], jsel[wid], lane, thr1, Mf1);
    {
        float oacc = 0.f;
        #pragma unroll
        for (int u = 0; u < 16; ++u) {
            int i = half * 16 + u;
            oacc = fmaf(wsel[wid][i], vbase[(size_t)jsel[wid][i] * AD + dd], oacc);
        }
        oacc += __shfl_down(oacc, 32);
        if (lane < HD) O[((size_t)b * S_ + r0 + 1) * AD + h * HD + lane] = oacc;
    }
}

__global__ __launch_bounds__(256)
void concat_kernel()
{
    int i = blockIdx.x * 256 + threadIdx.x;   // over 8192*256
    int row = i >> 8, c = i & 255;
    float v = (c < AD) ? g_ws[OFF_T + row * AD + c]
                       : g_ws[OFF_SB + row * AD + (c - AD)];
    g_ws[OFF_CAT + i] = v;
}

__global__ __launch_bounds__(256)
void fuse_kernel(float* __restrict__ out)
{
    int i = blockIdx.x * 256 + threadIdx.x;   // over 8192*128
    float g = g_ws[OFF_Q + i];
    float f = g_ws[OFF_K + i];
    out[i] = f / (1.0f + expf(-g));           // f * sigmoid(g)
}

extern "C" void kernel_launch(void* const* d_in, const int* in_sizes, int n_in,
                              void* d_out, int out_size, void* d_ws, size_t ws_size,
                              hipStream_t stream)
{
    (void)in_sizes; (void)n_in; (void)d_ws; (void)ws_size; (void)out_size;
    const float* x      = (const float*)d_in[0];
    const float* tp_w   = (const float*)d_in[1];
    const float* tp_b   = (const float*)d_in[2];
    const float* sp_w   = (const float*)d_in[3];
    const float* sp_b   = (const float*)d_in[4];
    const float* gate_w = (const float*)d_in[21];
    const float* gate_b = (const float*)d_in[22];
    const float* fus_w  = (const float*)d_in[23];
    const float* fus_b  = (const float*)d_in[24];

    dim3 gl(128, 2);
    for (int br = 0; br < 2; ++br) {
        const float* pw = br ? sp_w : tp_w;
        const float* pb = br ? sp_b : tp_b;
        int base = 5 + br * 8;
        const float* qw = (const float*)d_in[base + 0];
        const float* qb = (const float*)d_in[base + 1];
        const float* kw = (const float*)d_in[base + 2];
        const float* kb = (const float*)d_in[base + 3];
        const float* vw = (const float*)d_in[base + 4];
        const float* vb = (const float*)d_in[base + 5];
        const float* ow = (const float*)d_in[base + 6];
        const float* ob = (const float*)d_in[base + 7];

        lin_kernel<256><<<gl, 256, 0, stream>>>(x, 0, pw, pb, OFF_PROJ);
        lin3_kernel<128><<<dim3(128, 2, 3), 256, 0, stream>>>(
            OFF_PROJ, qw, qb, OFF_Q, kw, kb, OFF_K, vw, vb, OFF_V);
        fused_attn<<<dim3(256, 16), 256, 0, stream>>>(OFF_Q, OFF_K, OFF_V, OFF_ATT);
        lin_kernel<128><<<gl, 256, 0, stream>>>(nullptr, OFF_ATT, ow, ob,
                                                br ? OFF_SB : OFF_T);
    }
    concat_kernel<<<8192, 256, 0, stream>>>();
    lin3_kernel<256><<<dim3(128, 2, 2), 256, 0, stream>>>(
        OFF_CAT, gate_w, gate_b, OFF_Q, fus_w, fus_b, OFF_K,
        (const float*)nullptr, (const float*)nullptr, 0);
    fuse_kernel<<<4096, 256, 0, stream>>>((float*)d_out);
}

// Round 9
// 403.691 us; speedup vs baseline: 1.9650x; 1.9650x over previous
//
#include <hip/hip_runtime.h>
#include <math.h>

#define B_   4
#define S_   2048
#define AD   128
#define NH   4
#define HD   32
#define TK   32
#define SEG  1048576            /* 8192*128 */
#define CAP  192                /* survivor capacity per wave */

#define OFF_PROJ 0
#define OFF_QT  (1 * SEG)
#define OFF_KT  (2 * SEG)
#define OFF_VT  (3 * SEG)
#define OFF_QS  (4 * SEG)
#define OFF_KS  (5 * SEG)
#define OFF_VS  (6 * SEG)
#define OFF_AT  (7 * SEG)       /* attn out, temporal */
#define OFF_AS  (8 * SEG)       /* attn out, semantic */
#define OFF_T   (9 * SEG)       /* o-proj out, temporal */
#define OFF_SB  (10 * SEG)      /* o-proj out, semantic */
#define OFF_CAT (11 * SEG)      /* 2*SEG floats */

__device__ float g_ws[13 * SEG];
__device__ float g_sc[2][8 * S_ * S_];   /* double-buffered 8-head score chunks */

__device__ __forceinline__ unsigned f2key(float s) {
    unsigned u = __float_as_uint(s);
    return (u & 0x80000000u) ? ~u : (u | 0x80000000u);
}
__device__ __forceinline__ float key2f(unsigned k) {
    unsigned u = (k & 0x80000000u) ? (k & 0x7FFFFFFFu) : ~k;
    return __uint_as_float(u);
}

// Y[M x 128] = X[M x KD] @ W[128 x KD]^T + b  (R5 known-good, pad 68)
template <int KD>
__global__ __launch_bounds__(256)
void lin_kernel(const float* __restrict__ Xext, int xoff,
                const float* __restrict__ W, const float* __restrict__ Bv,
                int yoff)
{
    const float* X = Xext ? Xext : (const float*)(g_ws + xoff);
    float* Y = g_ws + yoff;
    __shared__ float Xs[32][68];
    __shared__ float Ws[32][68];
    const int bm = blockIdx.x * 64;
    const int bn = blockIdx.y * 64;
    const int t  = threadIdx.x;
    const int tx = t & 15, ty = t >> 4;
    const int sr = t >> 3, sc4 = t & 7;
    float acc[4][4] = {};
    for (int kk = 0; kk < KD; kk += 32) {
        #pragma unroll
        for (int it = 0; it < 2; ++it) {
            int rr = sr + it * 32;
            float4 xa = *(const float4*)(X + (size_t)(bm + rr) * KD + kk + sc4 * 4);
            float4 wa = *(const float4*)(W + (size_t)(bn + rr) * KD + kk + sc4 * 4);
            Xs[sc4*4+0][rr] = xa.x; Xs[sc4*4+1][rr] = xa.y;
            Xs[sc4*4+2][rr] = xa.z; Xs[sc4*4+3][rr] = xa.w;
            Ws[sc4*4+0][rr] = wa.x; Ws[sc4*4+1][rr] = wa.y;
            Ws[sc4*4+2][rr] = wa.z; Ws[sc4*4+3][rr] = wa.w;
        }
        __syncthreads();
        #pragma unroll
        for (int kc = 0; kc < 32; ++kc) {
            float4 a4 = *(const float4*)&Xs[kc][ty * 4];
            float4 b4 = *(const float4*)&Ws[kc][tx * 4];
            float a[4] = {a4.x, a4.y, a4.z, a4.w};
            float bb[4] = {b4.x, b4.y, b4.z, b4.w};
            #pragma unroll
            for (int i = 0; i < 4; ++i)
                #pragma unroll
                for (int j = 0; j < 4; ++j)
                    acc[i][j] = fmaf(a[i], bb[j], acc[i][j]);
        }
        __syncthreads();
    }
    #pragma unroll
    for (int i = 0; i < 4; ++i) {
        int row = bm + ty * 4 + i;
        int col = bn + tx * 4;
        float4 o;
        o.x = acc[i][0] + Bv[col + 0]; o.y = acc[i][1] + Bv[col + 1];
        o.z = acc[i][2] + Bv[col + 2]; o.w = acc[i][3] + Bv[col + 3];
        *(float4*)(Y + (size_t)row * AD + col) = o;
    }
}

template <int KD>
__global__ __launch_bounds__(256)
void lin3_kernel(int xoff,
                 const float* __restrict__ W0, const float* __restrict__ B0, int y0,
                 const float* __restrict__ W1, const float* __restrict__ B1, int y1,
                 const float* __restrict__ W2, const float* __restrict__ B2, int y2)
{
    const int z = blockIdx.z;
    const float* X = (const float*)(g_ws + xoff);
    const float* W = (z == 0) ? W0 : (z == 1) ? W1 : W2;
    const float* Bv = (z == 0) ? B0 : (z == 1) ? B1 : B2;
    float* Y = g_ws + ((z == 0) ? y0 : (z == 1) ? y1 : y2);
    __shared__ float Xs[32][68];
    __shared__ float Ws[32][68];
    const int bm = blockIdx.x * 64;
    const int bn = blockIdx.y * 64;
    const int t  = threadIdx.x;
    const int tx = t & 15, ty = t >> 4;
    const int sr = t >> 3, sc4 = t & 7;
    float acc[4][4] = {};
    for (int kk = 0; kk < KD; kk += 32) {
        #pragma unroll
        for (int it = 0; it < 2; ++it) {
            int rr = sr + it * 32;
            float4 xa = *(const float4*)(X + (size_t)(bm + rr) * KD + kk + sc4 * 4);
            float4 wa = *(const float4*)(W + (size_t)(bn + rr) * KD + kk + sc4 * 4);
            Xs[sc4*4+0][rr] = xa.x; Xs[sc4*4+1][rr] = xa.y;
            Xs[sc4*4+2][rr] = xa.z; Xs[sc4*4+3][rr] = xa.w;
            Ws[sc4*4+0][rr] = wa.x; Ws[sc4*4+1][rr] = wa.y;
            Ws[sc4*4+2][rr] = wa.z; Ws[sc4*4+3][rr] = wa.w;
        }
        __syncthreads();
        #pragma unroll
        for (int kc = 0; kc < 32; ++kc) {
            float4 a4 = *(const float4*)&Xs[kc][ty * 4];
            float4 b4 = *(const float4*)&Ws[kc][tx * 4];
            float a[4] = {a4.x, a4.y, a4.z, a4.w};
            float bb[4] = {b4.x, b4.y, b4.z, b4.w};
            #pragma unroll
            for (int i = 0; i < 4; ++i)
                #pragma unroll
                for (int j = 0; j < 4; ++j)
                    acc[i][j] = fmaf(a[i], bb[j], acc[i][j]);
        }
        __syncthreads();
    }
    #pragma unroll
    for (int i = 0; i < 4; ++i) {
        int row = bm + ty * 4 + i;
        int col = bn + tx * 4;
        float4 o;
        o.x = acc[i][0] + Bv[col + 0]; o.y = acc[i][1] + Bv[col + 1];
        o.z = acc[i][2] + Bv[col + 2]; o.w = acc[i][3] + Bv[col + 3];
        *(float4*)(Y + (size_t)row * AD + col) = o;
    }
}

// Dual-role kernel: score blocks and topk blocks co-resident in ONE dispatch.
// Roles interleaved 2:1 via blockIdx%3 so CUs mix both roles immediately.
// Score writes buf s_buf (chunk s_chunk of branch with s_qoff/s_koff);
// topk reads buf t_buf (chunk t_chunk, previous launch's output) -> no race.
__global__ __launch_bounds__(256)
void pipe_kernel(int nscore, int ntopk,
                 int s_qoff, int s_koff, int s_chunk, int s_buf,
                 int t_voff, int t_ooff, int t_chunk, int t_buf)
{
    __shared__ __align__(16) unsigned char smem[17408];  // union: score 17408 / topk 7168
    const int bid = blockIdx.x;
    bool isScore;
    int rid;
    if (nscore > 0 && ntopk > 0) {
        if ((bid % 3) == 2) { isScore = false; rid = bid / 3; }
        else                { isScore = true;  rid = (bid / 3) * 2 + (bid % 3); }
    } else if (nscore > 0) { isScore = true;  rid = bid; }
    else                   { isScore = false; rid = bid; }

    if (isScore) {
        // ================= score role (R5 body) =================
        float (*Qs)[68] = (float(*)[68])smem;
        float (*Ks)[68] = (float(*)[68])(smem + 8704);
        const int kx = rid & 31, qy = (rid >> 5) & 31, zh = rid >> 10;
        const int hh = s_chunk * 8 + zh, b = hh >> 2, h = hh & 3;
        const float* Qb = g_ws + s_qoff + (size_t)b * S_ * AD + h * HD;
        const float* Kb = g_ws + s_koff + (size_t)b * S_ * AD + h * HD;
        float* Sc = g_sc[s_buf] + (size_t)zh * S_ * S_;
        const int t = threadIdx.x, tx = t & 15, ty = t >> 4;
        const int sr = t >> 3, sc4 = t & 7;
        const int q0 = qy * 64, k0 = kx * 64;
        #pragma unroll
        for (int it = 0; it < 2; ++it) {
            int rr = sr + it * 32;
            float4 qa = *(const float4*)(Qb + (size_t)(q0 + rr) * AD + sc4 * 4);
            float4 ka = *(const float4*)(Kb + (size_t)(k0 + rr) * AD + sc4 * 4);
            Qs[sc4*4+0][rr] = qa.x; Qs[sc4*4+1][rr] = qa.y;
            Qs[sc4*4+2][rr] = qa.z; Qs[sc4*4+3][rr] = qa.w;
            Ks[sc4*4+0][rr] = ka.x; Ks[sc4*4+1][rr] = ka.y;
            Ks[sc4*4+2][rr] = ka.z; Ks[sc4*4+3][rr] = ka.w;
        }
        __syncthreads();
        float acc[4][4] = {};
        #pragma unroll
        for (int kc = 0; kc < 32; ++kc) {
            float4 a4 = *(const float4*)&Qs[kc][ty * 4];
            float4 b4 = *(const float4*)&Ks[kc][tx * 4];
            float a[4] = {a4.x, a4.y, a4.z, a4.w};
            float bb[4] = {b4.x, b4.y, b4.z, b4.w};
            #pragma unroll
            for (int i = 0; i < 4; ++i)
                #pragma unroll
                for (int j = 0; j < 4; ++j)
                    acc[i][j] = fmaf(a[i], bb[j], acc[i][j]);
        }
        const float scale = 0.17677669529663688f;  // 1/sqrt(32)
        #pragma unroll
        for (int i = 0; i < 4; ++i) {
            float4 o;
            o.x = acc[i][0] * scale; o.y = acc[i][1] * scale;
            o.z = acc[i][2] * scale; o.w = acc[i][3] * scale;
            *(float4*)(Sc + (size_t)(q0 + ty * 4 + i) * S_ + k0 + tx * 4) = o;
        }
    } else {
        // ================= topk role (R5 body) =================
        unsigned long long* sve = (unsigned long long*)smem;           // 4*CAP*8 = 6144
        float*    wsel = (float*)(smem + 6144);                        // 512
        unsigned* jsel = (unsigned*)(smem + 6656);                     // 512
        const float* V = g_ws + t_voff;
        float* O = g_ws + t_ooff;

        const int wid  = threadIdx.x >> 6;
        const int lane = threadIdx.x & 63;
        const int gr   = rid * 4 + wid;          // 0..16383
        const int zh   = gr >> 11, q = gr & 2047;
        const int hh   = t_chunk * 8 + zh;
        const int b    = hh >> 2,  h = hh & 3;

        unsigned long long* sv = sve + wid * CAP;
        float*    wp = wsel + wid * 32;
        unsigned* jp = jsel + wid * 32;

        const float* Srow  = g_sc[t_buf] + (size_t)zh * S_ * S_ + (size_t)q * S_;
        const float* vbase = V + (size_t)b * S_ * AD + h * HD;

        float4 s4[8];
        #pragma unroll
        for (int i = 0; i < 8; ++i) s4[i] = ((const float4*)Srow)[i * 64 + lane];
        unsigned keys[32];
        unsigned lmax = 0u;
        #pragma unroll
        for (int i = 0; i < 8; ++i) {
            unsigned k0 = f2key(s4[i].x), k1 = f2key(s4[i].y);
            unsigned k2 = f2key(s4[i].z), k3 = f2key(s4[i].w);
            keys[i * 4 + 0] = k0; keys[i * 4 + 1] = k1;
            keys[i * 4 + 2] = k2; keys[i * 4 + 3] = k3;
            unsigned m01 = (k0 > k1) ? k0 : k1;
            unsigned m23 = (k2 > k3) ? k2 : k3;
            unsigned m = (m01 > m23) ? m01 : m23;
            lmax = (m > lmax) ? m : lmax;
        }

        unsigned bs = lmax;
        #pragma unroll
        for (int k = 2; k <= 64; k <<= 1) {
            #pragma unroll
            for (int j = k >> 1; j > 0; j >>= 1) {
                unsigned o = (unsigned)__shfl_xor((int)bs, j);
                bool up = ((lane & k) == 0);
                bool lower = ((lane & j) == 0);
                bs = (up == lower) ? (bs < o ? bs : o) : (bs > o ? bs : o);
            }
        }
        const unsigned thr  = (unsigned)__shfl((int)bs, 32);
        const unsigned mkey = (unsigned)__shfl((int)bs, 63);
        const float Mf = key2f(mkey);

        int base = 0;
        const unsigned long long lt = (1ull << lane) - 1ull;
        #pragma unroll
        for (int t = 0; t < 32; ++t) {
            bool pred = keys[t] >= thr;
            unsigned long long m = __ballot(pred);
            int slot = base + __popcll(m & lt);
            if (pred && slot < CAP) {
                unsigned jidx = (unsigned)((t >> 2) * 256 + lane * 4 + (t & 3));
                sv[slot] = ((unsigned long long)keys[t] << 32) | (unsigned)(2047 - jidx);
            }
            base += __popcll(m);
        }
        const int S = base;
        asm volatile("s_waitcnt lgkmcnt(0)" ::: "memory");

        if (S <= 64) {
            unsigned long long pi = (lane < S) ? sv[lane] : 0ull;
            int rank = 0;
            for (int jx = 0; jx < S; ++jx)
                rank += (sv[jx] > pi) ? 1 : 0;
            float e = 0.f; unsigned ji = 0;
            if (lane < S && rank < TK) {
                float val = key2f((unsigned)(pi >> 32));
                e = __expf(val - Mf);
                ji = 2047u - (unsigned)(pi & 0xFFFFFFFFull);
            }
            float esum = e;
            #pragma unroll
            for (int off = 1; off < 64; off <<= 1) esum += __shfl_xor(esum, off);
            if (lane < S && rank < TK) { wp[rank] = e / esum; jp[rank] = ji; }
        } else if (S <= CAP) {
            unsigned long long pi[3]; int rk[3]; float ee[3]; unsigned jj[3];
            float esum = 0.f;
            #pragma unroll
            for (int u = 0; u < 3; ++u) {
                int i = lane + u * 64;
                pi[u] = (i < S) ? sv[i] : 0ull;
                rk[u] = 0; ee[u] = 0.f; jj[u] = 0;
            }
            for (int jx = 0; jx < S; ++jx) {
                unsigned long long pj = sv[jx];
                #pragma unroll
                for (int u = 0; u < 3; ++u)
                    rk[u] += (pj > pi[u]) ? 1 : 0;
            }
            #pragma unroll
            for (int u = 0; u < 3; ++u) {
                int i = lane + u * 64;
                if (i < S && rk[u] < TK) {
                    float val = key2f((unsigned)(pi[u] >> 32));
                    ee[u] = __expf(val - Mf);
                    jj[u] = 2047u - (unsigned)(pi[u] & 0xFFFFFFFFull);
                    esum += ee[u];
                }
            }
            #pragma unroll
            for (int off = 1; off < 64; off <<= 1) esum += __shfl_xor(esum, off);
            #pragma unroll
            for (int u = 0; u < 3; ++u) {
                int i = lane + u * 64;
                if (i < S && rk[u] < TK) { wp[rk[u]] = ee[u] / esum; jp[rk[u]] = jj[u]; }
            }
        } else {
            unsigned consumed = 0u;
            for (int i = 0; i < TK; ++i) {
                unsigned bk = 0u; unsigned gj = 0xFFFFFFFFu;
                #pragma unroll
                for (int t = 0; t < 32; ++t) {
                    if (((consumed >> t) & 1u) == 0u) {
                        unsigned kk = keys[t];
                        unsigned j = (unsigned)((t >> 2) * 256 + lane * 4 + (t & 3));
                        if (kk > bk || (kk == bk && j < gj)) { bk = kk; gj = j; }
                    }
                }
                #pragma unroll
                for (int off = 1; off < 64; off <<= 1) {
                    unsigned ok = (unsigned)__shfl_xor((int)bk, off);
                    unsigned oj = (unsigned)__shfl_xor((int)gj, off);
                    if (ok > bk || (ok == bk && oj < gj)) { bk = ok; gj = oj; }
                }
                if (((gj >> 2) & 63u) == (unsigned)lane && gj != 0xFFFFFFFFu) {
                    int t = ((int)gj >> 8) * 4 + ((int)gj & 3);
                    consumed |= (1u << t);
                }
                if (lane == 0) { wp[i] = key2f(bk); jp[i] = gj; }
            }
            asm volatile("s_waitcnt lgkmcnt(0)" ::: "memory");
            float v = (lane < TK) ? wp[lane] : 0.f;
            float e = (lane < TK) ? __expf(v - Mf) : 0.f;
            float esum = e;
            #pragma unroll
            for (int off = 1; off < 64; off <<= 1) esum += __shfl_xor(esum, off);
            if (lane < TK) wp[lane] = e / esum;
        }
        asm volatile("s_waitcnt lgkmcnt(0)" ::: "memory");

        float oacc = 0.f;
        const int dd = lane & 31, half = lane >> 5;
        #pragma unroll
        for (int u2 = 0; u2 < 16; ++u2) {
            int i = half * 16 + u2;
            oacc = fmaf(wp[i], vbase[(size_t)jp[i] * AD + dd], oacc);
        }
        oacc += __shfl_down(oacc, 32);
        if (lane < HD) O[((size_t)b * S_ + q) * AD + h * HD + lane] = oacc;
    }
}

__global__ __launch_bounds__(256)
void concat_kernel()
{
    int i = blockIdx.x * 256 + threadIdx.x;   // over 8192*256
    int row = i >> 8, c = i & 255;
    float v = (c < AD) ? g_ws[OFF_T + row * AD + c]
                       : g_ws[OFF_SB + row * AD + (c - AD)];
    g_ws[OFF_CAT + i] = v;
}

__global__ __launch_bounds__(256)
void fuse_kernel(float* __restrict__ out)
{
    int i = blockIdx.x * 256 + threadIdx.x;   // over 8192*128
    float g = g_ws[OFF_QT + i];
    float f = g_ws[OFF_KT + i];
    out[i] = f / (1.0f + expf(-g));           // f * sigmoid(g)
}

extern "C" void kernel_launch(void* const* d_in, const int* in_sizes, int n_in,
                              void* d_out, int out_size, void* d_ws, size_t ws_size,
                              hipStream_t stream)
{
    (void)in_sizes; (void)n_in; (void)d_ws; (void)ws_size; (void)out_size;
    const float* x      = (const float*)d_in[0];
    const float* tp_w   = (const float*)d_in[1];
    const float* tp_b   = (const float*)d_in[2];
    const float* sp_w   = (const float*)d_in[3];
    const float* sp_b   = (const float*)d_in[4];
    const float* gate_w = (const float*)d_in[21];
    const float* gate_b = (const float*)d_in[22];
    const float* fus_w  = (const float*)d_in[23];
    const float* fus_b  = (const float*)d_in[24];

    const float* ta_w[8]; const float* sa_w[8];
    for (int i = 0; i < 8; ++i) { ta_w[i] = (const float*)d_in[5 + i];
                                  sa_w[i] = (const float*)d_in[13 + i]; }

    dim3 gl(128, 2);
    // projections + QKV for BOTH branches first
    lin_kernel<256><<<gl, 256, 0, stream>>>(x, 0, tp_w, tp_b, OFF_PROJ);
    lin3_kernel<128><<<dim3(128, 2, 3), 256, 0, stream>>>(
        OFF_PROJ, ta_w[0], ta_w[1], OFF_QT, ta_w[2], ta_w[3], OFF_KT,
        ta_w[4], ta_w[5], OFF_VT);
    lin_kernel<256><<<gl, 256, 0, stream>>>(x, 0, sp_w, sp_b, OFF_PROJ);
    lin3_kernel<128><<<dim3(128, 2, 3), 256, 0, stream>>>(
        OFF_PROJ, sa_w[0], sa_w[1], OFF_QS, sa_w[2], sa_w[3], OFF_KS,
        sa_w[4], sa_w[5], OFF_VS);

    // software pipeline: score(next) || topk(prev) inside single dispatches
    pipe_kernel<<<8192, 256, 0, stream>>>(8192, 0,
        OFF_QT, OFF_KT, 0, 0,   0, 0, 0, 0);
    pipe_kernel<<<12288, 256, 0, stream>>>(8192, 4096,
        OFF_QT, OFF_KT, 1, 1,   OFF_VT, OFF_AT, 0, 0);
    pipe_kernel<<<12288, 256, 0, stream>>>(8192, 4096,
        OFF_QS, OFF_KS, 0, 0,   OFF_VT, OFF_AT, 1, 1);
    pipe_kernel<<<12288, 256, 0, stream>>>(8192, 4096,
        OFF_QS, OFF_KS, 1, 1,   OFF_VS, OFF_AS, 0, 0);
    pipe_kernel<<<4096, 256, 0, stream>>>(0, 4096,
        0, 0, 0, 0,             OFF_VS, OFF_AS, 1, 1);

    // output projections
    lin_kernel<128><<<gl, 256, 0, stream>>>(nullptr, OFF_AT, ta_w[6], ta_w[7], OFF_T);
    lin_kernel<128><<<gl, 256, 0, stream>>>(nullptr, OFF_AS, sa_w[6], sa_w[7], OFF_SB);

    concat_kernel<<<8192, 256, 0, stream>>>();
    lin3_kernel<256><<<dim3(128, 2, 2), 256, 0, stream>>>(
        OFF_CAT, gate_w, gate_b, OFF_QT, fus_w, fus_b, OFF_KT,
        (const float*)nullptr, (const float*)nullptr, 0);
    fuse_kernel<<<4096, 256, 0, stream>>>((float*)d_out);
}